// Round 5
// baseline (482.002 us; speedup 1.0000x reference)
//
#include <hip/hip_runtime.h>
#include <math.h>

// ---------------------------------------------------------------------------
// PermutedNetwork, R5: layout split by role.
//  - All conv/deform OUTPUTS are NCHW (dense per-instruction plane stores --
//    R4's NHWC stores caused 11x HBM write amplification, 637MB/dispatch).
//  - All gather INPUTS are NHWC (float4 over channels), produced by the pool
//    kernels which transpose NCHW->NHWC (cheap, L2-bound).
//  - Layer 1: LDS input tile + NCHW sector-aligned stores, launch_bounds(256,8).
// fp32 throughout (no fp32 MFMA on CDNA4).
// ---------------------------------------------------------------------------

// ---- Layer 1: fused offset-conv + deform + relu, CIN=1, NCHW out.
__global__ __launch_bounds__(256, 8)
void deform1_fused(const float* __restrict__ x,    // [64,96,96]
                   const float* __restrict__ woff, // [18,1,3,3]
                   const float* __restrict__ boff, // [18]
                   const float* __restrict__ w1,   // [16,1,3,3]
                   const float* __restrict__ b1,   // [16]
                   float* __restrict__ out) {      // [64,16,96,96] NCHW
  const int H = 96, W = 96, HW = H * W;
  __shared__ float tile[21 * 22];
  __shared__ float wos[9 * 18];
  __shared__ __align__(16) float ws1[9 * 16];
  int b = blockIdx.y;
  int tileid = blockIdx.x;                    // 0..35
  int by0 = (tileid / 6) * 16, bx0 = (tileid % 6) * 16;
  const float* xb = x + (size_t)b * HW;

  for (int t = threadIdx.x; t < 9 * 18; t += 256) { int k = t / 18, tc = t % 18; wos[t] = woff[tc * 9 + k]; }
  for (int t = threadIdx.x; t < 9 * 16; t += 256) { int k = t / 16, o = t % 16; ws1[t] = w1[o * 9 + k]; }
  for (int t = threadIdx.x; t < 21 * 21; t += 256) {
    int r = t / 21, c = t % 21;
    int gy = min(max(by0 - 2 + r, 0), H - 1);
    int gx = min(max(bx0 - 2 + c, 0), W - 1);
    tile[r * 22 + c] = xb[gy * W + gx];
  }
  __syncthreads();

  int tx = threadIdx.x & 15, ty = threadIdx.x >> 4;
  int yi = by0 + ty, xi = bx0 + tx;

  float off[18];
#pragma unroll
  for (int tc = 0; tc < 18; ++tc) off[tc] = boff[tc];
#pragma unroll
  for (int ky = 0; ky < 3; ++ky) {
    int yy = yi + ky - 1;
    if (yy < 0 || yy >= H) continue;
#pragma unroll
    for (int kx = 0; kx < 3; ++kx) {
      int xx = xi + kx - 1;
      if (xx < 0 || xx >= W) continue;
      float v = tile[(ty + ky + 1) * 22 + (tx + kx + 1)];
      const float2* wv = (const float2*)&wos[(ky * 3 + kx) * 18];
#pragma unroll
      for (int tt = 0; tt < 9; ++tt) {
        float2 ww = wv[tt];
        off[2 * tt]     = fmaf(ww.x, v, off[2 * tt]);
        off[2 * tt + 1] = fmaf(ww.y, v, off[2 * tt + 1]);
      }
    }
  }

  float acc[16];
#pragma unroll
  for (int o = 0; o < 16; ++o) acc[o] = b1[o];

#pragma unroll
  for (int k = 0; k < 9; ++k) {
    float py = (float)(yi + k / 3 - 1) + off[2 * k];
    float px = (float)(xi + k % 3 - 1) + off[2 * k + 1];
    float y0f = floorf(py), x0f = floorf(px);
    float fy = py - y0f, fx = px - x0f;
    int y0 = (int)y0f, x0 = (int)x0f, y1 = y0 + 1, x1 = x0 + 1;
    float vy0 = (y0 >= 0 && y0 < H) ? 1.f : 0.f;
    float vy1 = (y1 >= 0 && y1 < H) ? 1.f : 0.f;
    float vx0 = (x0 >= 0 && x0 < W) ? 1.f : 0.f;
    float vx1 = (x1 >= 0 && x1 < W) ? 1.f : 0.f;
    float w00 = (1.f - fy) * (1.f - fx) * vy0 * vx0;
    float w01 = (1.f - fy) * fx * vy0 * vx1;
    float w10 = fy * (1.f - fx) * vy1 * vx0;
    float w11 = fy * fx * vy1 * vx1;
    int cy0 = min(max(y0, 0), H - 1), cy1 = min(max(y1, 0), H - 1);
    int cx0 = min(max(x0, 0), W - 1), cx1 = min(max(x1, 0), W - 1);
    float v00, v01, v10, v11;
    bool in_lds = (cy0 >= by0 - 2) && (cy1 <= by0 + 18) && (cx0 >= bx0 - 2) && (cx1 <= bx0 + 18);
    if (in_lds) {
      int r0 = cy0 - by0 + 2, r1 = cy1 - by0 + 2;
      int c0 = cx0 - bx0 + 2, c1 = cx1 - bx0 + 2;
      v00 = tile[r0 * 22 + c0]; v01 = tile[r0 * 22 + c1];
      v10 = tile[r1 * 22 + c0]; v11 = tile[r1 * 22 + c1];
    } else {
      v00 = xb[cy0 * W + cx0]; v01 = xb[cy0 * W + cx1];
      v10 = xb[cy1 * W + cx0]; v11 = xb[cy1 * W + cx1];
    }
    float val = w00 * v00 + w01 * v01 + w10 * v10 + w11 * v11;
    const float4* wv = (const float4*)&ws1[k * 16];
#pragma unroll
    for (int q = 0; q < 4; ++q) {
      float4 w4 = wv[q];
      acc[4 * q + 0] = fmaf(w4.x, val, acc[4 * q + 0]);
      acc[4 * q + 1] = fmaf(w4.y, val, acc[4 * q + 1]);
      acc[4 * q + 2] = fmaf(w4.z, val, acc[4 * q + 2]);
      acc[4 * q + 3] = fmaf(w4.w, val, acc[4 * q + 3]);
    }
  }

  float* op = out + (size_t)b * 16 * HW + (size_t)yi * W + xi;
#pragma unroll
  for (int o = 0; o < 16; ++o)
    op[(size_t)o * HW] = fmaxf(acc[o], 0.f);   // dense 64B sectors per 16 lanes
}

// ---- 2x2 maxpool, NCHW in -> NHWC out. Lanes cover channels fastest (dense
// float4 writes); NCHW reads are L2-resident scalars.
template <int C, int HI>
__global__ void pool_nchw_to_nhwc(const float* __restrict__ in,  // [B,C,HI,HI]
                                  float* __restrict__ out) {     // [B,HO,HO,C]
  const int HO = HI / 2, C4 = C / 4;
  int gid = blockIdx.x * blockDim.x + threadIdx.x;
  if (gid >= 64 * HO * HO * C4) return;
  int c4 = gid % C4;
  int t = gid / C4;
  int x = t % HO; t /= HO;
  int y = t % HO;
  int b = t / HO;
  float4 r;
  float* rp = &r.x;
#pragma unroll
  for (int cc = 0; cc < 4; ++cc) {
    int c = c4 * 4 + cc;
    const float* p = in + ((size_t)(b * C + c) * HI + 2 * y) * HI + 2 * x;
    rp[cc] = fmaxf(fmaxf(p[0], p[1]), fmaxf(p[HI], p[HI + 1]));
  }
  *(float4*)(out + (((size_t)b * HO + y) * HO + x) * C + c4 * 4) = r;
}

// ---- 3x3 conv: NHWC in, NCHW out, no activation.
template <int CIN, int COUT, int NSPLIT>
__global__ __launch_bounds__(256, 4)
void conv3x3_hwc_chw(const float* __restrict__ in,  // [B,H,W,CIN]
                     const float* __restrict__ w,   // [COUT,CIN,3,3]
                     const float* __restrict__ bias,
                     float* __restrict__ out,       // [B,COUT,H,W]
                     int B, int H, int W) {
  constexpr int OC = COUT / NSPLIT;
  __shared__ float ws[9 * CIN * OC];
  int obase = blockIdx.y * OC;
  for (int t = threadIdx.x; t < 9 * CIN * OC; t += 256) {
    int k = t / (CIN * OC); int r = t % (CIN * OC);
    int c = r / OC; int o = r % OC;
    ws[t] = w[((obase + o) * CIN + c) * 9 + k];
  }
  __syncthreads();

  int gid = blockIdx.x * 256 + threadIdx.x;
  if (gid >= B * H * W) return;
  int x = gid % W; int t0 = gid / W; int y = t0 % H; int b = t0 / H;
  int HW = H * W;
  const float* inb = in + (size_t)b * HW * CIN;

  float acc[OC];
#pragma unroll
  for (int o = 0; o < OC; ++o) acc[o] = bias[obase + o];

#pragma unroll
  for (int ky = 0; ky < 3; ++ky) {
    int yy = y + ky - 1;
    if (yy < 0 || yy >= H) continue;
#pragma unroll
    for (int kx = 0; kx < 3; ++kx) {
      int xx = x + kx - 1;
      if (xx < 0 || xx >= W) continue;
      const float4* p4 = (const float4*)(inb + ((size_t)yy * W + xx) * CIN);
      int k = ky * 3 + kx;
#pragma unroll
      for (int c4 = 0; c4 < CIN / 4; ++c4) {
        float4 p = p4[c4];
        const float* pv = &p.x;
#pragma unroll
        for (int cc = 0; cc < 4; ++cc) {
          const float* wrow = &ws[(k * CIN + 4 * c4 + cc) * OC];
#pragma unroll
          for (int o = 0; o < OC; ++o) acc[o] = fmaf(wrow[o], pv[cc], acc[o]);
        }
      }
    }
  }

  float* op = out + (size_t)b * COUT * HW + (size_t)obase * HW + (size_t)y * W + x;
#pragma unroll
  for (int o = 0; o < OC; ++o) op[(size_t)o * HW] = acc[o];
}

// ---- Deformable 3x3 conv + ReLU: NHWC in, NCHW offsets, NCHW out.
template <int CIN, int COUT, int NSPLIT>
__global__ __launch_bounds__(256, 4)
void deform_hwc_chw(const float* __restrict__ in,     // [B,H,W,CIN]
                    const float* __restrict__ off_in, // [B,18,H,W]
                    const float* __restrict__ w,      // [COUT,CIN,3,3]
                    const float* __restrict__ bias,
                    float* __restrict__ out,          // [B,COUT,H,W]
                    int B, int H, int W) {
  constexpr int OC = COUT / NSPLIT;
  __shared__ __align__(16) float ws[9 * CIN * OC];
  int obase = blockIdx.y * OC;
  for (int t = threadIdx.x; t < 9 * CIN * OC; t += 256) {
    int k = t / (CIN * OC); int r = t % (CIN * OC);
    int c = r / OC; int o = r % OC;
    ws[t] = w[((obase + o) * CIN + c) * 9 + k];
  }
  __syncthreads();

  int gid = blockIdx.x * 256 + threadIdx.x;
  if (gid >= B * H * W) return;
  int xi = gid % W; int t0 = gid / W; int yi = t0 % H; int b = t0 / H;
  int HW = H * W;
  const float* inb = in + (size_t)b * HW * CIN;

  float off[18];
  const float* ofp = off_in + (size_t)b * 18 * HW + (size_t)yi * W + xi;
#pragma unroll
  for (int tc = 0; tc < 18; ++tc) off[tc] = ofp[(size_t)tc * HW];

  float acc[OC];
#pragma unroll
  for (int o = 0; o < OC; ++o) acc[o] = bias[obase + o];

#pragma unroll
  for (int k = 0; k < 9; ++k) {
    float py = (float)(yi + k / 3 - 1) + off[2 * k];
    float px = (float)(xi + k % 3 - 1) + off[2 * k + 1];
    float y0f = floorf(py), x0f = floorf(px);
    float fy = py - y0f, fx = px - x0f;
    int y0 = (int)y0f, x0 = (int)x0f, y1 = y0 + 1, x1 = x0 + 1;
    float vy0 = (y0 >= 0 && y0 < H) ? 1.f : 0.f;
    float vy1 = (y1 >= 0 && y1 < H) ? 1.f : 0.f;
    float vx0 = (x0 >= 0 && x0 < W) ? 1.f : 0.f;
    float vx1 = (x1 >= 0 && x1 < W) ? 1.f : 0.f;
    float w00 = (1.f - fy) * (1.f - fx) * vy0 * vx0;
    float w01 = (1.f - fy) * fx * vy0 * vx1;
    float w10 = fy * (1.f - fx) * vy1 * vx0;
    float w11 = fy * fx * vy1 * vx1;
    int cy0 = min(max(y0, 0), H - 1), cy1 = min(max(y1, 0), H - 1);
    int cx0 = min(max(x0, 0), W - 1), cx1 = min(max(x1, 0), W - 1);
    const float4* p00 = (const float4*)(inb + ((size_t)cy0 * W + cx0) * CIN);
    const float4* p01 = (const float4*)(inb + ((size_t)cy0 * W + cx1) * CIN);
    const float4* p10 = (const float4*)(inb + ((size_t)cy1 * W + cx0) * CIN);
    const float4* p11 = (const float4*)(inb + ((size_t)cy1 * W + cx1) * CIN);

#pragma unroll
    for (int c8 = 0; c8 < CIN / 8; ++c8) {
      // batch 2 channel-quads x 4 corners = 8 independent float4 loads
      float4 a0 = p00[2 * c8], b0 = p01[2 * c8], c0 = p10[2 * c8], d0 = p11[2 * c8];
      float4 a1 = p00[2 * c8 + 1], b1 = p01[2 * c8 + 1], c1 = p10[2 * c8 + 1], d1 = p11[2 * c8 + 1];
      float vals[8];
      vals[0] = w00 * a0.x + w01 * b0.x + w10 * c0.x + w11 * d0.x;
      vals[1] = w00 * a0.y + w01 * b0.y + w10 * c0.y + w11 * d0.y;
      vals[2] = w00 * a0.z + w01 * b0.z + w10 * c0.z + w11 * d0.z;
      vals[3] = w00 * a0.w + w01 * b0.w + w10 * c0.w + w11 * d0.w;
      vals[4] = w00 * a1.x + w01 * b1.x + w10 * c1.x + w11 * d1.x;
      vals[5] = w00 * a1.y + w01 * b1.y + w10 * c1.y + w11 * d1.y;
      vals[6] = w00 * a1.z + w01 * b1.z + w10 * c1.z + w11 * d1.z;
      vals[7] = w00 * a1.w + w01 * b1.w + w10 * c1.w + w11 * d1.w;
#pragma unroll
      for (int cc = 0; cc < 8; ++cc) {
        const float4* wv = (const float4*)&ws[(k * CIN + 8 * c8 + cc) * OC];
#pragma unroll
        for (int q = 0; q < OC / 4; ++q) {
          float4 w4 = wv[q];
          acc[4 * q + 0] = fmaf(w4.x, vals[cc], acc[4 * q + 0]);
          acc[4 * q + 1] = fmaf(w4.y, vals[cc], acc[4 * q + 1]);
          acc[4 * q + 2] = fmaf(w4.z, vals[cc], acc[4 * q + 2]);
          acc[4 * q + 3] = fmaf(w4.w, vals[cc], acc[4 * q + 3]);
        }
      }
    }
  }

  float* op = out + (size_t)b * COUT * HW + (size_t)obase * HW + (size_t)yi * W + xi;
#pragma unroll
  for (int o = 0; o < OC; ++o) op[(size_t)o * HW] = fmaxf(acc[o], 0.f);
}

// ---- Adaptive avg pool 24->3 (8x8 bins) + fc(576->10), NCHW input.
__global__ void poolfc_kernel(const float* __restrict__ h,   // [B,64,24,24]
                              const float* __restrict__ wfc, // [10,576]
                              const float* __restrict__ bfc, // [10]
                              float* __restrict__ out) {     // [B,10]
  __shared__ float feat[576];
  int b = blockIdx.x;
  int f = threadIdx.x; // 576 threads
  int c = f / 9, ij = f % 9, i = ij / 3, j = ij % 3;
  const float* p = h + ((size_t)(b * 64 + c) * 24 + i * 8) * 24 + j * 8;
  float s = 0.f;
#pragma unroll
  for (int r = 0; r < 8; ++r)
#pragma unroll
    for (int q = 0; q < 8; ++q)
      s += p[r * 24 + q];
  feat[f] = s * (1.f / 64.f);
  __syncthreads();
  if (f < 10) {
    float acc = bfc[f];
    const float* wp = wfc + f * 576;
    for (int t = 0; t < 576; ++t) acc = fmaf(wp[t], feat[t], acc);
    out[b * 10 + f] = acc;
  }
}

extern "C" void kernel_launch(void* const* d_in, const int* in_sizes, int n_in,
                              void* d_out, int out_size, void* d_ws, size_t ws_size,
                              hipStream_t stream) {
  const float* x      = (const float*)d_in[0];
  const float* w_off1 = (const float*)d_in[1];
  const float* b_off1 = (const float*)d_in[2];
  const float* w1     = (const float*)d_in[3];
  const float* b1     = (const float*)d_in[4];
  const float* w_off2 = (const float*)d_in[5];
  const float* b_off2 = (const float*)d_in[6];
  const float* w2     = (const float*)d_in[7];
  const float* b2     = (const float*)d_in[8];
  const float* w_off3 = (const float*)d_in[9];
  const float* b_off3 = (const float*)d_in[10];
  const float* w3     = (const float*)d_in[11];
  const float* b3     = (const float*)d_in[12];
  const float* w_fc   = (const float*)d_in[13];
  const float* b_fc   = (const float*)d_in[14];
  float* out = (float*)d_out;

  char* ws = (char*)d_ws;
  float* A  = (float*)(ws);               // NCHW conv/deform outputs (<=37.75MB)
  float* Bp = (float*)(ws + 37748736);    // NHWC pooled inputs (<=9.44MB)
  float* Cp = (float*)(ws + 47185920);    // NCHW offsets (<=10.62MB)

  const int thr = 256;

  // Layer 1: fused offset+deform+relu -> A [64,16,96,96] NCHW
  deform1_fused<<<dim3(36, 64), thr, 0, stream>>>(x, w_off1, b_off1, w1, b1, A);
  // pool -> Bp [64,48,48,16] NHWC
  {
    int total = 64 * 48 * 48 * 4;
    pool_nchw_to_nhwc<16, 96><<<(total + thr - 1) / thr, thr, 0, stream>>>(A, Bp);
  }

  // Layer 2: offset conv -> Cp [64,18,48,48] NCHW   (576 blocks)
  conv3x3_hwc_chw<16, 18, 1><<<dim3(576, 1), thr, 0, stream>>>(Bp, w_off2, b_off2, Cp, 64, 48, 48);
  // deform + relu -> A [64,32,48,48] NCHW           (NSPLIT=2, 1152 blocks)
  deform_hwc_chw<16, 32, 2><<<dim3(576, 2), thr, 0, stream>>>(Bp, Cp, w2, b2, A, 64, 48, 48);
  // pool -> Bp [64,24,24,32] NHWC
  {
    int total = 64 * 24 * 24 * 8;
    pool_nchw_to_nhwc<32, 48><<<(total + thr - 1) / thr, thr, 0, stream>>>(A, Bp);
  }

  // Layer 3: offset conv -> Cp [64,18,24,24] NCHW   (NSPLIT=3, 432 blocks)
  conv3x3_hwc_chw<32, 18, 3><<<dim3(144, 3), thr, 0, stream>>>(Bp, w_off3, b_off3, Cp, 64, 24, 24);
  // deform + relu -> A [64,64,24,24] NCHW           (NSPLIT=4, 576 blocks)
  deform_hwc_chw<32, 64, 4><<<dim3(144, 4), thr, 0, stream>>>(Bp, Cp, w3, b3, A, 64, 24, 24);

  // avgpool(3x3) + fc -> out [64,10]
  poolfc_kernel<<<64, 576, 0, stream>>>(A, w_fc, b_fc, out);
}

// Round 6
// 265.481 us; speedup vs baseline: 1.8156x; 1.8156x over previous
//
#include <hip/hip_runtime.h>
#include <math.h>

// ---------------------------------------------------------------------------
// PermutedNetwork, R6.
// R4/R5 lesson (counters): __launch_bounds__(256,6/8) forced VGPR to 40/32 <
// live set (off[18]+acc[16]) -> scratch spills in HBM -> 500-750 MB traffic.
// Fix: NO launch_bounds on deform1 (natural ~110 VGPR), linear gid mapping
// (dense wave stores, R3-proven 1x write volume), 2 px/thread for gather MLP.
// Rest of the net: R5 structure (pool transposes NCHW->NHWC; deform/conv
// gather NHWC float4, store NCHW dense).
// ---------------------------------------------------------------------------

// ---- Layer 1: fused offset-conv + deform + relu, CIN=1. 2 pixels/thread.
__global__ void deform1_fused(const float* __restrict__ x,    // [64,96,96]
                              const float* __restrict__ woff, // [18,1,3,3]
                              const float* __restrict__ boff, // [18]
                              const float* __restrict__ w1,   // [16,1,3,3]
                              const float* __restrict__ b1,   // [16]
                              float* __restrict__ out) {      // [64,16,96,96]
  const int H = 96, W = 96, HW = H * W;
  __shared__ float wos[9 * 18];
  __shared__ __align__(16) float ws1[9 * 16];
  for (int t = threadIdx.x; t < 9 * 18; t += 256) { int k = t / 18, tc = t % 18; wos[t] = woff[tc * 9 + k]; }
  for (int t = threadIdx.x; t < 9 * 16; t += 256) { int k = t / 16, o = t % 16; ws1[t] = w1[o * 9 + k]; }
  __syncthreads();

  int gid = blockIdx.x * 256 + threadIdx.x;   // over B*HW/2, exact grid
  int p2 = gid % (HW / 2);
  int b  = gid / (HW / 2);
  int xi0 = (2 * p2) % W, yi = (2 * p2) / W;  // pixels (yi,xi0), (yi,xi0+1)
  const float* xb = x + (size_t)b * HW;

  // 3x4 input window (shared by both pixels' offset convs), masked clamp loads
  float v[3][4];
#pragma unroll
  for (int r = 0; r < 3; ++r) {
    int yy = yi + r - 1;
    float my = (yy >= 0 && yy < H) ? 1.f : 0.f;
    int cy = min(max(yy, 0), H - 1);
#pragma unroll
    for (int c = 0; c < 4; ++c) {
      int xx = xi0 + c - 1;
      float mx = (xx >= 0 && xx < W) ? 1.f : 0.f;
      int cx = min(max(xx, 0), W - 1);
      v[r][c] = xb[cy * W + cx] * (my * mx);
    }
  }

  float off0[18], off1[18];
#pragma unroll
  for (int tc = 0; tc < 18; ++tc) { float bb = boff[tc]; off0[tc] = bb; off1[tc] = bb; }
#pragma unroll
  for (int r = 0; r < 3; ++r)
#pragma unroll
    for (int c = 0; c < 3; ++c) {
      float t0 = v[r][c], t1 = v[r][c + 1];
      const float2* wv = (const float2*)&wos[(r * 3 + c) * 18];
#pragma unroll
      for (int tt = 0; tt < 9; ++tt) {
        float2 ww = wv[tt];
        off0[2 * tt]     = fmaf(ww.x, t0, off0[2 * tt]);
        off0[2 * tt + 1] = fmaf(ww.y, t0, off0[2 * tt + 1]);
        off1[2 * tt]     = fmaf(ww.x, t1, off1[2 * tt]);
        off1[2 * tt + 1] = fmaf(ww.y, t1, off1[2 * tt + 1]);
      }
    }

  float acc0[16], acc1[16];
#pragma unroll
  for (int o = 0; o < 16; ++o) { float bb = b1[o]; acc0[o] = bb; acc1[o] = bb; }

#pragma unroll
  for (int k = 0; k < 9; ++k) {
    int dky = k / 3 - 1, dkx = k % 3 - 1;
    // --- pixel 0 and pixel 1 bilinear taps (8 independent loads) ---
    float val0, val1;
    {
      float py = (float)(yi + dky) + off0[2 * k];
      float px = (float)(xi0 + dkx) + off0[2 * k + 1];
      float y0f = floorf(py), x0f = floorf(px);
      float fy = py - y0f, fx = px - x0f;
      int y0 = (int)y0f, x0 = (int)x0f, y1 = y0 + 1, x1 = x0 + 1;
      float vy0 = (y0 >= 0 && y0 < H) ? 1.f : 0.f;
      float vy1 = (y1 >= 0 && y1 < H) ? 1.f : 0.f;
      float vx0 = (x0 >= 0 && x0 < W) ? 1.f : 0.f;
      float vx1 = (x1 >= 0 && x1 < W) ? 1.f : 0.f;
      float w00 = (1.f - fy) * (1.f - fx) * vy0 * vx0;
      float w01 = (1.f - fy) * fx * vy0 * vx1;
      float w10 = fy * (1.f - fx) * vy1 * vx0;
      float w11 = fy * fx * vy1 * vx1;
      int cy0 = min(max(y0, 0), H - 1), cy1 = min(max(y1, 0), H - 1);
      int cx0 = min(max(x0, 0), W - 1), cx1 = min(max(x1, 0), W - 1);
      float a = xb[cy0 * W + cx0], bb = xb[cy0 * W + cx1];
      float c = xb[cy1 * W + cx0], d = xb[cy1 * W + cx1];
      val0 = w00 * a + w01 * bb + w10 * c + w11 * d;
    }
    {
      float py = (float)(yi + dky) + off1[2 * k];
      float px = (float)(xi0 + 1 + dkx) + off1[2 * k + 1];
      float y0f = floorf(py), x0f = floorf(px);
      float fy = py - y0f, fx = px - x0f;
      int y0 = (int)y0f, x0 = (int)x0f, y1 = y0 + 1, x1 = x0 + 1;
      float vy0 = (y0 >= 0 && y0 < H) ? 1.f : 0.f;
      float vy1 = (y1 >= 0 && y1 < H) ? 1.f : 0.f;
      float vx0 = (x0 >= 0 && x0 < W) ? 1.f : 0.f;
      float vx1 = (x1 >= 0 && x1 < W) ? 1.f : 0.f;
      float w00 = (1.f - fy) * (1.f - fx) * vy0 * vx0;
      float w01 = (1.f - fy) * fx * vy0 * vx1;
      float w10 = fy * (1.f - fx) * vy1 * vx0;
      float w11 = fy * fx * vy1 * vx1;
      int cy0 = min(max(y0, 0), H - 1), cy1 = min(max(y1, 0), H - 1);
      int cx0 = min(max(x0, 0), W - 1), cx1 = min(max(x1, 0), W - 1);
      float a = xb[cy0 * W + cx0], bb = xb[cy0 * W + cx1];
      float c = xb[cy1 * W + cx0], d = xb[cy1 * W + cx1];
      val1 = w00 * a + w01 * bb + w10 * c + w11 * d;
    }
    const float4* wv = (const float4*)&ws1[k * 16];
#pragma unroll
    for (int q = 0; q < 4; ++q) {
      float4 w4 = wv[q];
      acc0[4 * q + 0] = fmaf(w4.x, val0, acc0[4 * q + 0]);
      acc0[4 * q + 1] = fmaf(w4.y, val0, acc0[4 * q + 1]);
      acc0[4 * q + 2] = fmaf(w4.z, val0, acc0[4 * q + 2]);
      acc0[4 * q + 3] = fmaf(w4.w, val0, acc0[4 * q + 3]);
      acc1[4 * q + 0] = fmaf(w4.x, val1, acc1[4 * q + 0]);
      acc1[4 * q + 1] = fmaf(w4.y, val1, acc1[4 * q + 1]);
      acc1[4 * q + 2] = fmaf(w4.z, val1, acc1[4 * q + 2]);
      acc1[4 * q + 3] = fmaf(w4.w, val1, acc1[4 * q + 3]);
    }
  }

  float* op = out + (size_t)b * 16 * HW + (size_t)yi * W + xi0;
#pragma unroll
  for (int o = 0; o < 16; ++o) {
    float2 r = make_float2(fmaxf(acc0[o], 0.f), fmaxf(acc1[o], 0.f));
    *(float2*)(op + (size_t)o * HW) = r;   // wave: 512B dense per channel
  }
}

// ---- 2x2 maxpool, NCHW in -> NHWC out.
template <int C, int HI>
__global__ void pool_nchw_to_nhwc(const float* __restrict__ in,  // [B,C,HI,HI]
                                  float* __restrict__ out) {     // [B,HO,HO,C]
  const int HO = HI / 2, C4 = C / 4;
  int gid = blockIdx.x * blockDim.x + threadIdx.x;
  if (gid >= 64 * HO * HO * C4) return;
  int c4 = gid % C4;
  int t = gid / C4;
  int x = t % HO; t /= HO;
  int y = t % HO;
  int b = t / HO;
  float4 r;
  float* rp = &r.x;
#pragma unroll
  for (int cc = 0; cc < 4; ++cc) {
    int c = c4 * 4 + cc;
    const float* p = in + ((size_t)(b * C + c) * HI + 2 * y) * HI + 2 * x;
    rp[cc] = fmaxf(fmaxf(p[0], p[1]), fmaxf(p[HI], p[HI + 1]));
  }
  *(float4*)(out + (((size_t)b * HO + y) * HO + x) * C + c4 * 4) = r;
}

// ---- 3x3 conv: NHWC in, NCHW out, no activation.
template <int CIN, int COUT, int NSPLIT>
__global__ __launch_bounds__(256, 4)
void conv3x3_hwc_chw(const float* __restrict__ in,  // [B,H,W,CIN]
                     const float* __restrict__ w,   // [COUT,CIN,3,3]
                     const float* __restrict__ bias,
                     float* __restrict__ out,       // [B,COUT,H,W]
                     int B, int H, int W) {
  constexpr int OC = COUT / NSPLIT;
  __shared__ float ws[9 * CIN * OC];
  int obase = blockIdx.y * OC;
  for (int t = threadIdx.x; t < 9 * CIN * OC; t += 256) {
    int k = t / (CIN * OC); int r = t % (CIN * OC);
    int c = r / OC; int o = r % OC;
    ws[t] = w[((obase + o) * CIN + c) * 9 + k];
  }
  __syncthreads();

  int gid = blockIdx.x * 256 + threadIdx.x;
  if (gid >= B * H * W) return;
  int x = gid % W; int t0 = gid / W; int y = t0 % H; int b = t0 / H;
  int HW = H * W;
  const float* inb = in + (size_t)b * HW * CIN;

  float acc[OC];
#pragma unroll
  for (int o = 0; o < OC; ++o) acc[o] = bias[obase + o];

#pragma unroll
  for (int ky = 0; ky < 3; ++ky) {
    int yy = y + ky - 1;
    if (yy < 0 || yy >= H) continue;
#pragma unroll
    for (int kx = 0; kx < 3; ++kx) {
      int xx = x + kx - 1;
      if (xx < 0 || xx >= W) continue;
      const float4* p4 = (const float4*)(inb + ((size_t)yy * W + xx) * CIN);
      int k = ky * 3 + kx;
#pragma unroll
      for (int c4 = 0; c4 < CIN / 4; ++c4) {
        float4 p = p4[c4];
        const float* pv = &p.x;
#pragma unroll
        for (int cc = 0; cc < 4; ++cc) {
          const float* wrow = &ws[(k * CIN + 4 * c4 + cc) * OC];
#pragma unroll
          for (int o = 0; o < OC; ++o) acc[o] = fmaf(wrow[o], pv[cc], acc[o]);
        }
      }
    }
  }

  float* op = out + (size_t)b * COUT * HW + (size_t)obase * HW + (size_t)y * W + x;
#pragma unroll
  for (int o = 0; o < OC; ++o) op[(size_t)o * HW] = acc[o];
}

// ---- Deformable 3x3 conv + ReLU: NHWC in, NCHW offsets, NCHW out.
template <int CIN, int COUT, int NSPLIT>
__global__ __launch_bounds__(256, 4)
void deform_hwc_chw(const float* __restrict__ in,     // [B,H,W,CIN]
                    const float* __restrict__ off_in, // [B,18,H,W]
                    const float* __restrict__ w,      // [COUT,CIN,3,3]
                    const float* __restrict__ bias,
                    float* __restrict__ out,          // [B,COUT,H,W]
                    int B, int H, int W) {
  constexpr int OC = COUT / NSPLIT;
  __shared__ __align__(16) float ws[9 * CIN * OC];
  int obase = blockIdx.y * OC;
  for (int t = threadIdx.x; t < 9 * CIN * OC; t += 256) {
    int k = t / (CIN * OC); int r = t % (CIN * OC);
    int c = r / OC; int o = r % OC;
    ws[t] = w[((obase + o) * CIN + c) * 9 + k];
  }
  __syncthreads();

  int gid = blockIdx.x * 256 + threadIdx.x;
  if (gid >= B * H * W) return;
  int xi = gid % W; int t0 = gid / W; int yi = t0 % H; int b = t0 / H;
  int HW = H * W;
  const float* inb = in + (size_t)b * HW * CIN;

  float off[18];
  const float* ofp = off_in + (size_t)b * 18 * HW + (size_t)yi * W + xi;
#pragma unroll
  for (int tc = 0; tc < 18; ++tc) off[tc] = ofp[(size_t)tc * HW];

  float acc[OC];
#pragma unroll
  for (int o = 0; o < OC; ++o) acc[o] = bias[obase + o];

#pragma unroll
  for (int k = 0; k < 9; ++k) {
    float py = (float)(yi + k / 3 - 1) + off[2 * k];
    float px = (float)(xi + k % 3 - 1) + off[2 * k + 1];
    float y0f = floorf(py), x0f = floorf(px);
    float fy = py - y0f, fx = px - x0f;
    int y0 = (int)y0f, x0 = (int)x0f, y1 = y0 + 1, x1 = x0 + 1;
    float vy0 = (y0 >= 0 && y0 < H) ? 1.f : 0.f;
    float vy1 = (y1 >= 0 && y1 < H) ? 1.f : 0.f;
    float vx0 = (x0 >= 0 && x0 < W) ? 1.f : 0.f;
    float vx1 = (x1 >= 0 && x1 < W) ? 1.f : 0.f;
    float w00 = (1.f - fy) * (1.f - fx) * vy0 * vx0;
    float w01 = (1.f - fy) * fx * vy0 * vx1;
    float w10 = fy * (1.f - fx) * vy1 * vx0;
    float w11 = fy * fx * vy1 * vx1;
    int cy0 = min(max(y0, 0), H - 1), cy1 = min(max(y1, 0), H - 1);
    int cx0 = min(max(x0, 0), W - 1), cx1 = min(max(x1, 0), W - 1);
    const float4* p00 = (const float4*)(inb + ((size_t)cy0 * W + cx0) * CIN);
    const float4* p01 = (const float4*)(inb + ((size_t)cy0 * W + cx1) * CIN);
    const float4* p10 = (const float4*)(inb + ((size_t)cy1 * W + cx0) * CIN);
    const float4* p11 = (const float4*)(inb + ((size_t)cy1 * W + cx1) * CIN);

#pragma unroll
    for (int c8 = 0; c8 < CIN / 8; ++c8) {
      float4 a0 = p00[2 * c8], b0 = p01[2 * c8], c0 = p10[2 * c8], d0 = p11[2 * c8];
      float4 a1 = p00[2 * c8 + 1], b1 = p01[2 * c8 + 1], c1 = p10[2 * c8 + 1], d1 = p11[2 * c8 + 1];
      float vals[8];
      vals[0] = w00 * a0.x + w01 * b0.x + w10 * c0.x + w11 * d0.x;
      vals[1] = w00 * a0.y + w01 * b0.y + w10 * c0.y + w11 * d0.y;
      vals[2] = w00 * a0.z + w01 * b0.z + w10 * c0.z + w11 * d0.z;
      vals[3] = w00 * a0.w + w01 * b0.w + w10 * c0.w + w11 * d0.w;
      vals[4] = w00 * a1.x + w01 * b1.x + w10 * c1.x + w11 * d1.x;
      vals[5] = w00 * a1.y + w01 * b1.y + w10 * c1.y + w11 * d1.y;
      vals[6] = w00 * a1.z + w01 * b1.z + w10 * c1.z + w11 * d1.z;
      vals[7] = w00 * a1.w + w01 * b1.w + w10 * c1.w + w11 * d1.w;
#pragma unroll
      for (int cc = 0; cc < 8; ++cc) {
        const float4* wv = (const float4*)&ws[(k * CIN + 8 * c8 + cc) * OC];
#pragma unroll
        for (int q = 0; q < OC / 4; ++q) {
          float4 w4 = wv[q];
          acc[4 * q + 0] = fmaf(w4.x, vals[cc], acc[4 * q + 0]);
          acc[4 * q + 1] = fmaf(w4.y, vals[cc], acc[4 * q + 1]);
          acc[4 * q + 2] = fmaf(w4.z, vals[cc], acc[4 * q + 2]);
          acc[4 * q + 3] = fmaf(w4.w, vals[cc], acc[4 * q + 3]);
        }
      }
    }
  }

  float* op = out + (size_t)b * COUT * HW + (size_t)obase * HW + (size_t)yi * W + xi;
#pragma unroll
  for (int o = 0; o < OC; ++o) op[(size_t)o * HW] = fmaxf(acc[o], 0.f);
}

// ---- Adaptive avg pool 24->3 (8x8 bins) + fc(576->10), NCHW input.
__global__ void poolfc_kernel(const float* __restrict__ h,   // [B,64,24,24]
                              const float* __restrict__ wfc, // [10,576]
                              const float* __restrict__ bfc, // [10]
                              float* __restrict__ out) {     // [B,10]
  __shared__ float feat[576];
  int b = blockIdx.x;
  int f = threadIdx.x; // 576 threads
  int c = f / 9, ij = f % 9, i = ij / 3, j = ij % 3;
  const float* p = h + ((size_t)(b * 64 + c) * 24 + i * 8) * 24 + j * 8;
  float s = 0.f;
#pragma unroll
  for (int r = 0; r < 8; ++r)
#pragma unroll
    for (int q = 0; q < 8; ++q)
      s += p[r * 24 + q];
  feat[f] = s * (1.f / 64.f);
  __syncthreads();
  if (f < 10) {
    float acc = bfc[f];
    const float* wp = wfc + f * 576;
    for (int t = 0; t < 576; ++t) acc = fmaf(wp[t], feat[t], acc);
    out[b * 10 + f] = acc;
  }
}

extern "C" void kernel_launch(void* const* d_in, const int* in_sizes, int n_in,
                              void* d_out, int out_size, void* d_ws, size_t ws_size,
                              hipStream_t stream) {
  const float* x      = (const float*)d_in[0];
  const float* w_off1 = (const float*)d_in[1];
  const float* b_off1 = (const float*)d_in[2];
  const float* w1     = (const float*)d_in[3];
  const float* b1     = (const float*)d_in[4];
  const float* w_off2 = (const float*)d_in[5];
  const float* b_off2 = (const float*)d_in[6];
  const float* w2     = (const float*)d_in[7];
  const float* b2     = (const float*)d_in[8];
  const float* w_off3 = (const float*)d_in[9];
  const float* b_off3 = (const float*)d_in[10];
  const float* w3     = (const float*)d_in[11];
  const float* b3     = (const float*)d_in[12];
  const float* w_fc   = (const float*)d_in[13];
  const float* b_fc   = (const float*)d_in[14];
  float* out = (float*)d_out;

  char* ws = (char*)d_ws;
  float* A  = (float*)(ws);               // NCHW conv/deform outputs (<=37.75MB)
  float* Bp = (float*)(ws + 37748736);    // NHWC pooled inputs (<=9.44MB)
  float* Cp = (float*)(ws + 47185920);    // NCHW offsets (<=10.62MB)

  const int thr = 256;

  // Layer 1: fused offset+deform+relu -> A [64,16,96,96] NCHW (2 px/thread)
  deform1_fused<<<64 * 96 * 96 / 2 / thr, thr, 0, stream>>>(x, w_off1, b_off1, w1, b1, A);
  // pool -> Bp [64,48,48,16] NHWC
  {
    int total = 64 * 48 * 48 * 4;
    pool_nchw_to_nhwc<16, 96><<<(total + thr - 1) / thr, thr, 0, stream>>>(A, Bp);
  }

  // Layer 2: offset conv -> Cp [64,18,48,48] NCHW
  conv3x3_hwc_chw<16, 18, 1><<<dim3(576, 1), thr, 0, stream>>>(Bp, w_off2, b_off2, Cp, 64, 48, 48);
  // deform + relu -> A [64,32,48,48] NCHW   (NSPLIT=2)
  deform_hwc_chw<16, 32, 2><<<dim3(576, 2), thr, 0, stream>>>(Bp, Cp, w2, b2, A, 64, 48, 48);
  // pool -> Bp [64,24,24,32] NHWC
  {
    int total = 64 * 24 * 24 * 8;
    pool_nchw_to_nhwc<32, 48><<<(total + thr - 1) / thr, thr, 0, stream>>>(A, Bp);
  }

  // Layer 3: offset conv -> Cp [64,18,24,24] NCHW   (NSPLIT=3)
  conv3x3_hwc_chw<32, 18, 3><<<dim3(144, 3), thr, 0, stream>>>(Bp, w_off3, b_off3, Cp, 64, 24, 24);
  // deform + relu -> A [64,64,24,24] NCHW           (NSPLIT=4)
  deform_hwc_chw<32, 64, 4><<<dim3(144, 4), thr, 0, stream>>>(Bp, Cp, w3, b3, A, 64, 24, 24);

  // avgpool(3x3) + fc -> out [64,10]
  poolfc_kernel<<<64, 576, 0, stream>>>(A, w_fc, b_fc, out);
}